// Round 8
// baseline (590.734 us; speedup 1.0000x reference)
//
#include <hip/hip_runtime.h>
#include <math.h>

#define HIDDEN 768
#define HEADS 12
#define HD 64
#define SEQ 2048
#define BATCH 2
#define KK 204
#define QB 16
#define NTH 1024

typedef __attribute__((ext_vector_type(8))) short short8;
typedef __attribute__((ext_vector_type(4))) float f32x4;

// monotonic float->uint key (larger float => larger key)
__device__ __forceinline__ unsigned fkey(float f) {
    unsigned u = __float_as_uint(f);
    return u ^ ((unsigned)((int)u >> 31) | 0x80000000u);
}
__device__ __forceinline__ float fival(unsigned k) {
    unsigned u = k ^ ((k & 0x80000000u) ? 0x80000000u : 0xFFFFFFFFu);
    return __uint_as_float(u);
}
__device__ __forceinline__ unsigned short bf16h(float f) {
    unsigned u = __float_as_uint(f);
    return (unsigned short)((u + 0x7FFFu + ((u >> 16) & 1u)) >> 16);
}
__device__ __forceinline__ float bf16f(unsigned short h) {
    return __uint_as_float(((unsigned)h) << 16);
}

// swizzled fp32 score LDS index (float4-group XOR row&7) — row stride 2048 f32
#define SIDX(r,k) (((r)<<11) + (((((k)>>2) ^ ((r)&7))) << 2) + ((k)&3))

// ---------------------------------------------------------------------------
// Convert fp32 row-major [rows x 768] into MFMA fragment layout bf16 hi/lo.
// ---------------------------------------------------------------------------
__global__ __launch_bounds__(256)
void cvt_frag(const float* __restrict__ in, unsigned short* __restrict__ oh,
              unsigned short* __restrict__ ol, int rows)
{
    const int t = blockIdx.x * 256 + threadIdx.x;
    if (t >= rows * 96) return;
    const int lane = t & 63;
    const int kc   = (t >> 6) % 24;
    const int rblk = t / (24 * 64);
    const int r = rblk * 16 + (lane & 15);
    const int k = kc * 32 + (lane >> 4) * 8;
    const float4 a = *(const float4*)&in[(size_t)r * 768 + k];
    const float4 b = *(const float4*)&in[(size_t)r * 768 + k + 4];
    const float v[8] = {a.x, a.y, a.z, a.w, b.x, b.y, b.z, b.w};
    short8 sh, sl;
    #pragma unroll
    for (int j = 0; j < 8; ++j) {
        const unsigned short hh = bf16h(v[j]);
        sh[j] = (short)hh;
        sl[j] = (short)bf16h(v[j] - bf16f(hh));
    }
    *(short8*)&oh[(size_t)t * 8] = sh;
    *(short8*)&ol[(size_t)t * 8] = sl;
}

// Batched weight conversion: blockIdx.y selects which of the 4 weights.
__global__ __launch_bounds__(256)
void cvt_frag_w(const float* __restrict__ W0, const float* __restrict__ W1,
                const float* __restrict__ W2, const float* __restrict__ W3,
                unsigned short* __restrict__ o0h, unsigned short* __restrict__ o0l,
                unsigned short* __restrict__ o1h, unsigned short* __restrict__ o1l,
                unsigned short* __restrict__ o2h, unsigned short* __restrict__ o2l,
                unsigned short* __restrict__ o3h, unsigned short* __restrict__ o3l)
{
    const float* in; unsigned short *oh, *ol;
    switch (blockIdx.y) {
        case 0:  in = W0; oh = o0h; ol = o0l; break;
        case 1:  in = W1; oh = o1h; ol = o1l; break;
        case 2:  in = W2; oh = o2h; ol = o2l; break;
        default: in = W3; oh = o3h; ol = o3l; break;
    }
    const int t = blockIdx.x * 256 + threadIdx.x;
    if (t >= 768 * 96) return;
    const int lane = t & 63;
    const int kc   = (t >> 6) % 24;
    const int rblk = t / (24 * 64);
    const int r = rblk * 16 + (lane & 15);
    const int k = kc * 32 + (lane >> 4) * 8;
    const float4 a = *(const float4*)&in[(size_t)r * 768 + k];
    const float4 b = *(const float4*)&in[(size_t)r * 768 + k + 4];
    const float v[8] = {a.x, a.y, a.z, a.w, b.x, b.y, b.z, b.w};
    short8 sh, sl;
    #pragma unroll
    for (int j = 0; j < 8; ++j) {
        const unsigned short hh = bf16h(v[j]);
        sh[j] = (short)hh;
        sl[j] = (short)bf16h(v[j] - bf16f(hh));
    }
    *(short8*)&oh[(size_t)t * 8] = sh;
    *(short8*)&ol[(size_t)t * 8] = sl;
}

// ---------------------------------------------------------------------------
// Fused Q/K/V projection via split-bf16 MFMA: blockIdx.z selects weight set.
// ---------------------------------------------------------------------------
__global__ __launch_bounds__(256)
void proj_fused(const unsigned short* __restrict__ Ah, const unsigned short* __restrict__ Al,
                const unsigned short* __restrict__ Wqh, const unsigned short* __restrict__ Wql,
                const unsigned short* __restrict__ Wkh, const unsigned short* __restrict__ Wkl,
                const unsigned short* __restrict__ Wvh, const unsigned short* __restrict__ Wvl,
                const float* __restrict__ bq, const float* __restrict__ bk,
                const float* __restrict__ bv,
                unsigned short* __restrict__ Qh, unsigned short* __restrict__ Ql,
                unsigned short* __restrict__ Kh, unsigned short* __restrict__ Kl,
                unsigned short* __restrict__ Vt)
{
    const unsigned short *Bh, *Bl; const float* bias;
    unsigned short *Oh, *Ol; int mode;
    if (blockIdx.z == 0)      { Bh = Wqh; Bl = Wql; bias = bq; Oh = Qh; Ol = Ql; mode = 0; }
    else if (blockIdx.z == 1) { Bh = Wkh; Bl = Wkl; bias = bk; Oh = Kh; Ol = Kl; mode = 0; }
    else                      { Bh = Wvh; Bl = Wvl; bias = bv; Oh = Vt; Ol = 0;  mode = 1; }

    const int w = threadIdx.x >> 6, lane = threadIdx.x & 63;
    const int n0 = blockIdx.x * 64;
    const int m0 = blockIdx.y * 64 + w * 16;
    const int mblk = m0 >> 4;
    f32x4 acc[4] = {};
    for (int kc = 0; kc < 24; ++kc) {
        const short8 ah = *(const short8*)&Ah[((size_t)(mblk * 24 + kc) * 64 + lane) * 8];
        const short8 al = *(const short8*)&Al[((size_t)(mblk * 24 + kc) * 64 + lane) * 8];
        #pragma unroll
        for (int nt = 0; nt < 4; ++nt) {
            const int nblk = (n0 >> 4) + nt;
            const short8 bh8 = *(const short8*)&Bh[((size_t)(nblk * 24 + kc) * 64 + lane) * 8];
            const short8 bl8 = *(const short8*)&Bl[((size_t)(nblk * 24 + kc) * 64 + lane) * 8];
            acc[nt] = __builtin_amdgcn_mfma_f32_16x16x32_bf16(ah, bh8, acc[nt], 0, 0, 0);
            acc[nt] = __builtin_amdgcn_mfma_f32_16x16x32_bf16(ah, bl8, acc[nt], 0, 0, 0);
            acc[nt] = __builtin_amdgcn_mfma_f32_16x16x32_bf16(al, bh8, acc[nt], 0, 0, 0);
        }
    }
    const int col = lane & 15, rg = lane >> 4;
    #pragma unroll
    for (int nt = 0; nt < 4; ++nt) {
        const int n = n0 + nt * 16 + col;
        const int h = n >> 6, dh = n & 63;
        const float bb = bias[n];
        #pragma unroll
        for (int r = 0; r < 4; ++r) {
            const int m = m0 + rg * 4 + r;
            const int b = m >> 11, s = m & (SEQ - 1);
            const float v = acc[nt][r] + bb;
            const unsigned short vh = bf16h(v);
            if (mode == 0) {
                const int t = s >> 4, colq = s & 15;
                const int ks = dh >> 5, kg = (dh >> 3) & 3, j = dh & 7;
                const size_t addr = ((((size_t)(b * HEADS + h) * 128 + t) * 2 + ks) * 64 + kg * 16 + colq) * 8 + j;
                Oh[addr] = vh;
                Ol[addr] = bf16h(v - bf16f(vh));
            } else {
                const int dt = dh >> 4, colv = dh & 15;
                const int kc2 = s >> 5, kg = (s >> 3) & 3, j = s & 7;
                const size_t addr = ((((size_t)(b * HEADS + h) * 4 + dt) * 64 + kc2) * 64 + kg * 16 + colv) * 8 + j;
                Oh[addr] = vh;
            }
        }
    }
}

// ---------------------------------------------------------------------------
// Output GEMM: out = AO @ Wo^T + bo (fp32 out), AO/Wo in fragment layout.
// ---------------------------------------------------------------------------
__global__ __launch_bounds__(256)
void gemm_out(const unsigned short* __restrict__ Ah, const unsigned short* __restrict__ Al,
              const unsigned short* __restrict__ Bh, const unsigned short* __restrict__ Bl,
              const float* __restrict__ bias, float* __restrict__ out)
{
    const int w = threadIdx.x >> 6, lane = threadIdx.x & 63;
    const int n0 = blockIdx.x * 64;
    const int m0 = blockIdx.y * 64 + w * 16;
    const int mblk = m0 >> 4;
    f32x4 acc[4] = {};
    for (int kc = 0; kc < 24; ++kc) {
        const short8 ah = *(const short8*)&Ah[((size_t)(mblk * 24 + kc) * 64 + lane) * 8];
        const short8 al = *(const short8*)&Al[((size_t)(mblk * 24 + kc) * 64 + lane) * 8];
        #pragma unroll
        for (int nt = 0; nt < 4; ++nt) {
            const int nblk = (n0 >> 4) + nt;
            const short8 bh8 = *(const short8*)&Bh[((size_t)(nblk * 24 + kc) * 64 + lane) * 8];
            const short8 bl8 = *(const short8*)&Bl[((size_t)(nblk * 24 + kc) * 64 + lane) * 8];
            acc[nt] = __builtin_amdgcn_mfma_f32_16x16x32_bf16(ah, bh8, acc[nt], 0, 0, 0);
            acc[nt] = __builtin_amdgcn_mfma_f32_16x16x32_bf16(ah, bl8, acc[nt], 0, 0, 0);
            acc[nt] = __builtin_amdgcn_mfma_f32_16x16x32_bf16(al, bh8, acc[nt], 0, 0, 0);
        }
    }
    const int col = lane & 15, rg = lane >> 4;
    #pragma unroll
    for (int nt = 0; nt < 4; ++nt) {
        const int n = n0 + nt * 16 + col;
        const float bb = bias[n];
        #pragma unroll
        for (int r = 0; r < 4; ++r) {
            const int m = m0 + rg * 4 + r;
            out[(size_t)m * HIDDEN + n] = acc[nt][r] + bb;
        }
    }
}

// ---------------------------------------------------------------------------
// Fused sparse attention. Select phase = register-only bisection with
// ballot-popcount counts (no LDS atomics, no histograms, 4 barriers total).
// XCD-aware work swizzle for K/V L2 residency.
// ---------------------------------------------------------------------------
__global__ __launch_bounds__(NTH, 4)
void sparse_attn(const unsigned short* __restrict__ Qfh, const unsigned short* __restrict__ Qfl,
                 const unsigned short* __restrict__ Kfh, const unsigned short* __restrict__ Kfl,
                 const unsigned short* __restrict__ Vf,
                 unsigned short* __restrict__ AOh, unsigned short* __restrict__ AOl)
{
    extern __shared__ float smem[];
    float*    scores = smem;                           // 16*2048 f32 swizzled; later Ph/Pl overlay
    unsigned* hist   = (unsigned*)(smem + QB * SEQ);   // PV partial-C buffer (16KB)
    unsigned* state  = hist + QB * 256;                // 16*8 (only [5]=inv used cross-wave)

    // ---- XCD-aware work remap (3072 = 8 XCDs x 384 work items)
    const int f = blockIdx.x + 128 * (blockIdx.y + 12 * blockIdx.z);
    const int wk = (f & 7) * 384 + (f >> 3);
    const int qb = wk & 127;
    const int h  = (wk >> 7) % 12;
    const int b  = wk / 1536;
    const int q0 = qb * QB;
    const int bh = b * HEADS + h;

    const int tid = threadIdx.x;
    const int wv = tid >> 6, lane = tid & 63;

    // ---- Phase A: scores = Q K^T / 8 (6 MFMA per 16x16 tile), 8 tiles/wave
    {
        const size_t qbase = ((size_t)bh * 128 + qb) * 1024;
        const short8 qh0 = *(const short8*)&Qfh[qbase + lane * 8];
        const short8 qh1 = *(const short8*)&Qfh[qbase + 512 + lane * 8];
        const short8 ql0 = *(const short8*)&Qfl[qbase + lane * 8];
        const short8 ql1 = *(const short8*)&Qfl[qbase + 512 + lane * 8];
        const int col = lane & 15, rg = lane >> 4;
        for (int i = 0; i < 8; ++i) {
            const int t = wv * 8 + i;
            const size_t kb = ((size_t)bh * 128 + t) * 1024 + lane * 8;
            const short8 kh0 = *(const short8*)&Kfh[kb];
            const short8 kh1 = *(const short8*)&Kfh[kb + 512];
            const short8 kl0 = *(const short8*)&Kfl[kb];
            const short8 kl1 = *(const short8*)&Kfl[kb + 512];
            f32x4 c = {};
            c = __builtin_amdgcn_mfma_f32_16x16x32_bf16(qh0, kh0, c, 0, 0, 0);
            c = __builtin_amdgcn_mfma_f32_16x16x32_bf16(qh1, kh1, c, 0, 0, 0);
            c = __builtin_amdgcn_mfma_f32_16x16x32_bf16(qh0, kl0, c, 0, 0, 0);
            c = __builtin_amdgcn_mfma_f32_16x16x32_bf16(qh1, kl1, c, 0, 0, 0);
            c = __builtin_amdgcn_mfma_f32_16x16x32_bf16(ql0, kh0, c, 0, 0, 0);
            c = __builtin_amdgcn_mfma_f32_16x16x32_bf16(ql1, kh1, c, 0, 0, 0);
            const int k = t * 16 + col;
            #pragma unroll
            for (int r = 0; r < 4; ++r) {
                const int row = rg * 4 + r;
                scores[SIDX(row, k)] = c[r] * 0.125f;
            }
        }
    }
    __syncthreads();     // barrier 1: cross-wave score transpose complete

    // ---- key load: row = wave, 32 keys/lane (conflict-free b128 reads)
    const int row = wv, rt = lane;
    unsigned* st = state + row * 8;
    const int cx = row & 7;
    unsigned key[32];
    {
        const float4* srow4 = (const float4*)(scores + (row << 11));
        #pragma unroll
        for (int j = 0; j < 8; ++j) {
            const float4 v = srow4[rt + 64 * j];
            key[4*j+0] = fkey(v.x); key[4*j+1] = fkey(v.y);
            key[4*j+2] = fkey(v.z); key[4*j+3] = fkey(v.w);
        }
    }
    __syncthreads();     // barrier 2: ALL keys in regs; scores LDS may be overlaid

    // ---- row max
    unsigned mk = 0;
    #pragma unroll
    for (int e = 0; e < 32; ++e) mk = max(mk, key[e]);
    #pragma unroll
    for (int d = 32; d >= 1; d >>= 1)
        mk = max(mk, (unsigned)__shfl_xor((int)mk, d, 64));
    const float mrow = fival(mk);

    // ---- exact top-KK threshold via 32-bit bisection, ballot-popcount counts
    // invariant: t in [lo, hi]; count(key > t) < KK <= count(key >= t)
    unsigned lo = 0, hi = mk;
    #pragma unroll 1
    while (lo < hi) {
        const unsigned mid = lo + ((hi - lo) >> 1);
        unsigned c = 0;
        #pragma unroll
        for (int e = 0; e < 32; ++e)
            c += (unsigned)__builtin_popcountll(__ballot(key[e] > mid));
        if (c >= KK) lo = mid + 1; else hi = mid;
    }
    const unsigned t = lo;
    unsigned cnt_gt = 0, cnt_eq = 0;
    #pragma unroll
    for (int e = 0; e < 32; ++e) {
        cnt_gt += (unsigned)__builtin_popcountll(__ballot(key[e] > t));
        cnt_eq += (unsigned)__builtin_popcountll(__ballot(key[e] == t));
    }
    const unsigned rem_eq = KK - cnt_gt;   // #elements ==t to include (>=1)

    // ---- tie handling (lowest-index-first, like lax.top_k); rare
    int icut = SEQ;
    if (cnt_eq > rem_eq) {
        unsigned eqm = 0;
        #pragma unroll
        for (int e = 0; e < 32; ++e)
            if (key[e] == t) eqm |= 1u << e;
        unsigned lo2 = 0, hi2 = SEQ - 1;
        #pragma unroll 1
        while (lo2 < hi2) {
            const unsigned mid = (lo2 + hi2) >> 1;
            unsigned c = 0;
            #pragma unroll
            for (int e = 0; e < 32; ++e) {
                const int gx = (rt + 64 * (e >> 2)) ^ cx;
                const unsigned idx = 4 * gx + (e & 3);
                c += (unsigned)__builtin_popcountll(
                        __ballot(((eqm >> e) & 1u) && idx <= mid));
            }
            if (c >= rem_eq) hi2 = mid; else lo2 = mid + 1;
        }
        icut = (int)lo2;
    }

    // ---- P = exp(s - m) on selected, 0 elsewhere; bf16 hi/lo overlay + denom
    unsigned short* PH = (unsigned short*)smem;
    unsigned short* PL = PH + QB * SEQ;
    {
        float psum = 0.f;
        #pragma unroll
        for (int j = 0; j < 8; ++j) {
            const int G = rt + 64 * j;
            const int gx = G ^ cx;
            unsigned short ph[4], pl[4];
            #pragma unroll
            for (int e = 0; e < 4; ++e) {
                const unsigned u = key[4*j+e];
                const int k = 4 * gx + e;
                float pv = 0.f;
                if (u > t || (u == t && k <= icut)) { pv = __expf(fival(u) - mrow); psum += pv; }
                const unsigned short hh = bf16h(pv);
                ph[e] = hh;
                pl[e] = bf16h(pv - bf16f(hh));
            }
            const int g16 = (gx >> 1) ^ cx;
            const int off = (row << 11) + (g16 << 3) + ((gx & 1) << 2);
            uint2 wph; wph.x = (unsigned)ph[0] | ((unsigned)ph[1] << 16);
            wph.y = (unsigned)ph[2] | ((unsigned)ph[3] << 16);
            *(uint2*)&PH[off] = wph;
            uint2 wpl; wpl.x = (unsigned)pl[0] | ((unsigned)pl[1] << 16);
            wpl.y = (unsigned)pl[2] | ((unsigned)pl[3] << 16);
            *(uint2*)&PL[off] = wpl;
        }
        #pragma unroll
        for (int d = 32; d >= 1; d >>= 1) psum += __shfl_xor(psum, d, 64);
        if (rt == 0) st[5] = __float_as_uint(1.0f / psum);
    }
    __syncthreads();     // barrier 3: all P stripes + denominators ready

    // ---- PV via MFMA: wave = (kv-slice kq, dh-tile dt); split P x bf16 V
    {
        const int dt = wv & 3, kq = wv >> 2;
        const int coll = lane & 15, kg = lane >> 4;
        const int c8 = coll & 7;
        f32x4 acc = {};
        for (int kc = 0; kc < 16; ++kc) {
            const int kv0 = kq * 512 + kc * 32 + kg * 8;
            const int aoff = (coll << 11) + (((kv0 >> 3) ^ c8) << 3);
            const short8 pa = *(const short8*)&PH[aoff];
            const short8 pb = *(const short8*)&PL[aoff];
            const int kc2 = kq * 16 + kc;
            const short8 bv = *(const short8*)&Vf[(((size_t)bh * 4 + dt) * 64 + kc2) * 512 + lane * 8];
            acc = __builtin_amdgcn_mfma_f32_16x16x32_bf16(pa, bv, acc, 0, 0, 0);
            acc = __builtin_amdgcn_mfma_f32_16x16x32_bf16(pb, bv, acc, 0, 0, 0);
        }
        float* red = (float*)hist;
        if (kq > 0) *(f32x4*)&red[(((kq - 1) * 4 + dt) * 64 + lane) << 2] = acc;
        __syncthreads();     // barrier 4: PV partials
        if (kq == 0) {
            #pragma unroll
            for (int q2 = 0; q2 < 3; ++q2) {
                const f32x4 o = *(const f32x4*)&red[((q2 * 4 + dt) * 64 + lane) << 2];
                acc[0] += o[0]; acc[1] += o[1]; acc[2] += o[2]; acc[3] += o[3];
            }
            #pragma unroll
            for (int r = 0; r < 4; ++r) {
                const int rw = (lane >> 4) * 4 + r;
                const float inv = __uint_as_float(state[rw * 8 + 5]);
                const float v = acc[r] * inv;
                const int n = h * 64 + dt * 16 + coll;
                const int m = b * SEQ + q0 + rw;
                const int mblk = m >> 4, mrow2 = m & 15;
                const int ks = n >> 5, kg2 = (n >> 3) & 3, j2 = n & 7;
                const size_t a2 = (((size_t)mblk * 24 + ks) * 64 + kg2 * 16 + mrow2) * 8 + j2;
                const unsigned short vh = bf16h(v);
                AOh[a2] = vh;
                AOl[a2] = bf16h(v - bf16f(vh));
            }
        }
    }
}

// ---------------------------------------------------------------------------
extern "C" void kernel_launch(void* const* d_in, const int* in_sizes, int n_in,
                              void* d_out, int out_size, void* d_ws, size_t ws_size,
                              hipStream_t stream)
{
    const float* x  = (const float*)d_in[0];
    const float* Wq = (const float*)d_in[1];
    const float* bq = (const float*)d_in[2];
    const float* Wk = (const float*)d_in[3];
    const float* bk = (const float*)d_in[4];
    const float* Wv = (const float*)d_in[5];
    const float* bv = (const float*)d_in[6];
    const float* Wo = (const float*)d_in[7];
    const float* bo = (const float*)d_in[8];

    unsigned short* U = (unsigned short*)d_ws;
    const size_t SZ = (size_t)BATCH * SEQ * HIDDEN;   // 3,145,728
    const size_t WSZ = (size_t)HIDDEN * HIDDEN;       //   589,824
    unsigned short* xh  = U;                // later reused as AOh
    unsigned short* xl  = U + SZ;           // later reused as AOl
    unsigned short* Qh  = U + 2 * SZ;
    unsigned short* Ql  = U + 3 * SZ;
    unsigned short* Kh  = U + 4 * SZ;
    unsigned short* Kl  = U + 5 * SZ;
    unsigned short* Vt  = U + 6 * SZ;
    unsigned short* wqh = U + 7 * SZ;
    unsigned short* wql = wqh + WSZ;
    unsigned short* wkh = wqh + 2 * WSZ;
    unsigned short* wkl = wqh + 3 * WSZ;
    unsigned short* wvh = wqh + 4 * WSZ;
    unsigned short* wvl = wqh + 5 * WSZ;
    unsigned short* woh = wqh + 6 * WSZ;
    unsigned short* wol = wqh + 7 * WSZ;

    const dim3 gg(HIDDEN / 64, (BATCH * SEQ) / 64);

    cvt_frag<<<1536, 256, 0, stream>>>(x, xh, xl, BATCH * SEQ);
    cvt_frag_w<<<dim3(288, 4), 256, 0, stream>>>(Wq, Wk, Wv, Wo,
        wqh, wql, wkh, wkl, wvh, wvl, woh, wol);

    proj_fused<<<dim3(HIDDEN / 64, (BATCH * SEQ) / 64, 3), 256, 0, stream>>>(
        xh, xl, wqh, wql, wkh, wkl, wvh, wvl, bq, bk, bv, Qh, Ql, Kh, Kl, Vt);

    const int shbytes = (QB * SEQ + QB * 256 + QB * 8) * 4;   // 147,968 B
    hipFuncSetAttribute((const void*)sparse_attn,
                        hipFuncAttributeMaxDynamicSharedMemorySize, shbytes);
    sparse_attn<<<dim3(SEQ / QB, HEADS, BATCH), NTH, shbytes, stream>>>(
        Qh, Ql, Kh, Kl, Vt, xh, xl);

    gemm_out<<<gg, 256, 0, stream>>>(xh, xl, woh, wol, bo, (float*)d_out);
}

// Round 9
// 535.736 us; speedup vs baseline: 1.1027x; 1.1027x over previous
//
#include <hip/hip_runtime.h>
#include <math.h>

#define HIDDEN 768
#define HEADS 12
#define HD 64
#define SEQ 2048
#define BATCH 2
#define KK 204
#define QB 16
#define NTH 1024

typedef __attribute__((ext_vector_type(8))) short short8;
typedef __attribute__((ext_vector_type(4))) float f32x4;

// monotonic float->uint key (larger float => larger key)
__device__ __forceinline__ unsigned fkey(float f) {
    unsigned u = __float_as_uint(f);
    return u ^ ((unsigned)((int)u >> 31) | 0x80000000u);
}
__device__ __forceinline__ float fival(unsigned k) {
    unsigned u = k ^ ((k & 0x80000000u) ? 0x80000000u : 0xFFFFFFFFu);
    return __uint_as_float(u);
}
__device__ __forceinline__ unsigned short bf16h(float f) {
    unsigned u = __float_as_uint(f);
    return (unsigned short)((u + 0x7FFFu + ((u >> 16) & 1u)) >> 16);
}
__device__ __forceinline__ float bf16f(unsigned short h) {
    return __uint_as_float(((unsigned)h) << 16);
}

// swizzled fp32 half-score LDS index (float4-group XOR row&7) — row stride 1024 f32
#define SIDXH(r,k) (((r)<<10) + (((((k)>>2) ^ ((r)&7))) << 2) + ((k)&3))

// ---------------------------------------------------------------------------
// Convert fp32 row-major [rows x 768] into MFMA fragment layout bf16 hi/lo.
// ---------------------------------------------------------------------------
__global__ __launch_bounds__(256)
void cvt_frag(const float* __restrict__ in, unsigned short* __restrict__ oh,
              unsigned short* __restrict__ ol, int rows)
{
    const int t = blockIdx.x * 256 + threadIdx.x;
    if (t >= rows * 96) return;
    const int lane = t & 63;
    const int kc   = (t >> 6) % 24;
    const int rblk = t / (24 * 64);
    const int r = rblk * 16 + (lane & 15);
    const int k = kc * 32 + (lane >> 4) * 8;
    const float4 a = *(const float4*)&in[(size_t)r * 768 + k];
    const float4 b = *(const float4*)&in[(size_t)r * 768 + k + 4];
    const float v[8] = {a.x, a.y, a.z, a.w, b.x, b.y, b.z, b.w};
    short8 sh, sl;
    #pragma unroll
    for (int j = 0; j < 8; ++j) {
        const unsigned short hh = bf16h(v[j]);
        sh[j] = (short)hh;
        sl[j] = (short)bf16h(v[j] - bf16f(hh));
    }
    *(short8*)&oh[(size_t)t * 8] = sh;
    *(short8*)&ol[(size_t)t * 8] = sl;
}

// Batched weight conversion: blockIdx.y selects which of the 4 weights.
__global__ __launch_bounds__(256)
void cvt_frag_w(const float* __restrict__ W0, const float* __restrict__ W1,
                const float* __restrict__ W2, const float* __restrict__ W3,
                unsigned short* __restrict__ o0h, unsigned short* __restrict__ o0l,
                unsigned short* __restrict__ o1h, unsigned short* __restrict__ o1l,
                unsigned short* __restrict__ o2h, unsigned short* __restrict__ o2l,
                unsigned short* __restrict__ o3h, unsigned short* __restrict__ o3l)
{
    const float* in; unsigned short *oh, *ol;
    switch (blockIdx.y) {
        case 0:  in = W0; oh = o0h; ol = o0l; break;
        case 1:  in = W1; oh = o1h; ol = o1l; break;
        case 2:  in = W2; oh = o2h; ol = o2l; break;
        default: in = W3; oh = o3h; ol = o3l; break;
    }
    const int t = blockIdx.x * 256 + threadIdx.x;
    if (t >= 768 * 96) return;
    const int lane = t & 63;
    const int kc   = (t >> 6) % 24;
    const int rblk = t / (24 * 64);
    const int r = rblk * 16 + (lane & 15);
    const int k = kc * 32 + (lane >> 4) * 8;
    const float4 a = *(const float4*)&in[(size_t)r * 768 + k];
    const float4 b = *(const float4*)&in[(size_t)r * 768 + k + 4];
    const float v[8] = {a.x, a.y, a.z, a.w, b.x, b.y, b.z, b.w};
    short8 sh, sl;
    #pragma unroll
    for (int j = 0; j < 8; ++j) {
        const unsigned short hh = bf16h(v[j]);
        sh[j] = (short)hh;
        sl[j] = (short)bf16h(v[j] - bf16f(hh));
    }
    *(short8*)&oh[(size_t)t * 8] = sh;
    *(short8*)&ol[(size_t)t * 8] = sl;
}

// ---------------------------------------------------------------------------
// Fused Q/K/V projection via split-bf16 MFMA: blockIdx.z selects weight set.
// z=0: Q (hi/lo), z=1: K (hi/lo), z=2: V (hi/lo, V fragment layout).
// ---------------------------------------------------------------------------
__global__ __launch_bounds__(256)
void proj_fused(const unsigned short* __restrict__ Ah, const unsigned short* __restrict__ Al,
                const unsigned short* __restrict__ Wqh, const unsigned short* __restrict__ Wql,
                const unsigned short* __restrict__ Wkh, const unsigned short* __restrict__ Wkl,
                const unsigned short* __restrict__ Wvh, const unsigned short* __restrict__ Wvl,
                const float* __restrict__ bq, const float* __restrict__ bk,
                const float* __restrict__ bv,
                unsigned short* __restrict__ Qh, unsigned short* __restrict__ Ql,
                unsigned short* __restrict__ Kh, unsigned short* __restrict__ Kl,
                unsigned short* __restrict__ Vth, unsigned short* __restrict__ Vtl)
{
    const unsigned short *Bh, *Bl; const float* bias;
    unsigned short *Oh, *Ol; int mode;
    if (blockIdx.z == 0)      { Bh = Wqh; Bl = Wql; bias = bq; Oh = Qh;  Ol = Ql;  mode = 0; }
    else if (blockIdx.z == 1) { Bh = Wkh; Bl = Wkl; bias = bk; Oh = Kh;  Ol = Kl;  mode = 0; }
    else                      { Bh = Wvh; Bl = Wvl; bias = bv; Oh = Vth; Ol = Vtl; mode = 1; }

    const int w = threadIdx.x >> 6, lane = threadIdx.x & 63;
    const int n0 = blockIdx.x * 64;
    const int m0 = blockIdx.y * 64 + w * 16;
    const int mblk = m0 >> 4;
    f32x4 acc[4] = {};
    for (int kc = 0; kc < 24; ++kc) {
        const short8 ah = *(const short8*)&Ah[((size_t)(mblk * 24 + kc) * 64 + lane) * 8];
        const short8 al = *(const short8*)&Al[((size_t)(mblk * 24 + kc) * 64 + lane) * 8];
        #pragma unroll
        for (int nt = 0; nt < 4; ++nt) {
            const int nblk = (n0 >> 4) + nt;
            const short8 bh8 = *(const short8*)&Bh[((size_t)(nblk * 24 + kc) * 64 + lane) * 8];
            const short8 bl8 = *(const short8*)&Bl[((size_t)(nblk * 24 + kc) * 64 + lane) * 8];
            acc[nt] = __builtin_amdgcn_mfma_f32_16x16x32_bf16(ah, bh8, acc[nt], 0, 0, 0);
            acc[nt] = __builtin_amdgcn_mfma_f32_16x16x32_bf16(ah, bl8, acc[nt], 0, 0, 0);
            acc[nt] = __builtin_amdgcn_mfma_f32_16x16x32_bf16(al, bh8, acc[nt], 0, 0, 0);
        }
    }
    const int col = lane & 15, rg = lane >> 4;
    #pragma unroll
    for (int nt = 0; nt < 4; ++nt) {
        const int n = n0 + nt * 16 + col;
        const int h = n >> 6, dh = n & 63;
        const float bb = bias[n];
        #pragma unroll
        for (int r = 0; r < 4; ++r) {
            const int m = m0 + rg * 4 + r;
            const int b = m >> 11, s = m & (SEQ - 1);
            const float v = acc[nt][r] + bb;
            const unsigned short vh = bf16h(v);
            if (mode == 0) {
                const int t = s >> 4, colq = s & 15;
                const int ks = dh >> 5, kg = (dh >> 3) & 3, j = dh & 7;
                const size_t addr = ((((size_t)(b * HEADS + h) * 128 + t) * 2 + ks) * 64 + kg * 16 + colq) * 8 + j;
                Oh[addr] = vh;
                Ol[addr] = bf16h(v - bf16f(vh));
            } else {
                const int dt = dh >> 4, colv = dh & 15;
                const int kc2 = s >> 5, kg = (s >> 3) & 3, j = s & 7;
                const size_t addr = ((((size_t)(b * HEADS + h) * 4 + dt) * 64 + kc2) * 64 + kg * 16 + colv) * 8 + j;
                Oh[addr] = vh;
                Ol[addr] = bf16h(v - bf16f(vh));
            }
        }
    }
}

// ---------------------------------------------------------------------------
// Output GEMM: out = AO @ Wo^T + bo (fp32 out), AO/Wo in fragment layout.
// ---------------------------------------------------------------------------
__global__ __launch_bounds__(256)
void gemm_out(const unsigned short* __restrict__ Ah, const unsigned short* __restrict__ Al,
              const unsigned short* __restrict__ Bh, const unsigned short* __restrict__ Bl,
              const float* __restrict__ bias, float* __restrict__ out)
{
    const int w = threadIdx.x >> 6, lane = threadIdx.x & 63;
    const int n0 = blockIdx.x * 64;
    const int m0 = blockIdx.y * 64 + w * 16;
    const int mblk = m0 >> 4;
    f32x4 acc[4] = {};
    for (int kc = 0; kc < 24; ++kc) {
        const short8 ah = *(const short8*)&Ah[((size_t)(mblk * 24 + kc) * 64 + lane) * 8];
        const short8 al = *(const short8*)&Al[((size_t)(mblk * 24 + kc) * 64 + lane) * 8];
        #pragma unroll
        for (int nt = 0; nt < 4; ++nt) {
            const int nblk = (n0 >> 4) + nt;
            const short8 bh8 = *(const short8*)&Bh[((size_t)(nblk * 24 + kc) * 64 + lane) * 8];
            const short8 bl8 = *(const short8*)&Bl[((size_t)(nblk * 24 + kc) * 64 + lane) * 8];
            acc[nt] = __builtin_amdgcn_mfma_f32_16x16x32_bf16(ah, bh8, acc[nt], 0, 0, 0);
            acc[nt] = __builtin_amdgcn_mfma_f32_16x16x32_bf16(ah, bl8, acc[nt], 0, 0, 0);
            acc[nt] = __builtin_amdgcn_mfma_f32_16x16x32_bf16(al, bh8, acc[nt], 0, 0, 0);
        }
    }
    const int col = lane & 15, rg = lane >> 4;
    #pragma unroll
    for (int nt = 0; nt < 4; ++nt) {
        const int n = n0 + nt * 16 + col;
        const float bb = bias[n];
        #pragma unroll
        for (int r = 0; r < 4; ++r) {
            const int m = m0 + rg * 4 + r;
            out[(size_t)m * HIDDEN + n] = acc[nt][r] + bb;
        }
    }
}

// ---------------------------------------------------------------------------
// Fused sparse attention, 2-blocks/CU edition: scores computed in two
// k-halves (64KB LDS), P stored single-bf16 (64KB overlay), split V in PV.
// Select = 16-bit bisection + exact candidate extraction (reg-only).
// ---------------------------------------------------------------------------
__global__ __launch_bounds__(NTH, 8)
void sparse_attn(const unsigned short* __restrict__ Qfh, const unsigned short* __restrict__ Qfl,
                 const unsigned short* __restrict__ Kfh, const unsigned short* __restrict__ Kfl,
                 const unsigned short* __restrict__ Vfh, const unsigned short* __restrict__ Vfl,
                 unsigned short* __restrict__ AOh, unsigned short* __restrict__ AOl)
{
    extern __shared__ float smem[];
    float*    scores = smem;                       // [16][1024] f32 / later PH [16][2048] bf16
    float*    red    = smem + 16 * 1024;           // PV partials (12KB)
    unsigned* state  = (unsigned*)(red + 3072);    // 16*8 (only [5]=inv cross-wave)

    // ---- XCD-aware work remap (3072 = 8 XCDs x 384 work items)
    const int f = blockIdx.x + 128 * (blockIdx.y + 12 * blockIdx.z);
    const int wk = (f & 7) * 384 + (f >> 3);
    const int qb = wk & 127;
    const int h  = (wk >> 7) % 12;
    const int b  = wk / 1536;
    const int q0 = qb * QB;
    const int bh = b * HEADS + h;

    const int tid = threadIdx.x;
    const int wv = tid >> 6, lane = tid & 63;
    const int row = wv, rt = lane;
    const int cx = row & 7;
    const int col = lane & 15, rg = lane >> 4;

    // ---- Q fragments (persist across both halves)
    const size_t qbase = ((size_t)bh * 128 + qb) * 1024;
    const short8 qh0 = *(const short8*)&Qfh[qbase + lane * 8];
    const short8 qh1 = *(const short8*)&Qfh[qbase + 512 + lane * 8];
    const short8 ql0 = *(const short8*)&Qfl[qbase + lane * 8];
    const short8 ql1 = *(const short8*)&Qfl[qbase + 512 + lane * 8];

    unsigned key[32];
    unsigned mk = 0;

    // ---- Phase A in two k-halves: scores -> 64KB LDS -> keys in VGPRs
    #pragma unroll 1
    for (int H = 0; H < 2; ++H) {
        for (int i = 0; i < 4; ++i) {
            const int tl = wv * 4 + i;            // tile within half (0..63)
            const int t = H * 64 + tl;
            const size_t kb = ((size_t)bh * 128 + t) * 1024 + lane * 8;
            const short8 kh0 = *(const short8*)&Kfh[kb];
            const short8 kh1 = *(const short8*)&Kfh[kb + 512];
            const short8 kl0 = *(const short8*)&Kfl[kb];
            const short8 kl1 = *(const short8*)&Kfl[kb + 512];
            f32x4 c = {};
            c = __builtin_amdgcn_mfma_f32_16x16x32_bf16(qh0, kh0, c, 0, 0, 0);
            c = __builtin_amdgcn_mfma_f32_16x16x32_bf16(ql0, kh0, c, 0, 0, 0);
            c = __builtin_amdgcn_mfma_f32_16x16x32_bf16(qh1, kh1, c, 0, 0, 0);
            c = __builtin_amdgcn_mfma_f32_16x16x32_bf16(ql1, kh1, c, 0, 0, 0);
            c = __builtin_amdgcn_mfma_f32_16x16x32_bf16(qh0, kl0, c, 0, 0, 0);
            c = __builtin_amdgcn_mfma_f32_16x16x32_bf16(qh1, kl1, c, 0, 0, 0);
            const int kl2 = tl * 16 + col;        // k within half
            #pragma unroll
            for (int r = 0; r < 4; ++r) {
                const int rr = rg * 4 + r;
                scores[SIDXH(rr, kl2)] = c[r] * 0.125f;
            }
        }
        __syncthreads();                          // half-scores ready
        {
            const float4* srow4 = (const float4*)(scores + (row << 10));
            #pragma unroll
            for (int j = 0; j < 4; ++j) {
                const float4 v = srow4[rt + 64 * j];
                unsigned k0 = fkey(v.x), k1 = fkey(v.y), k2 = fkey(v.z), k3 = fkey(v.w);
                key[H*16 + 4*j + 0] = k0; key[H*16 + 4*j + 1] = k1;
                key[H*16 + 4*j + 2] = k2; key[H*16 + 4*j + 3] = k3;
                mk = max(mk, max(max(k0, k1), max(k2, k3)));
            }
        }
        if (H == 0) __syncthreads();              // all keyloads done before overwrite
    }

    // ---- row max
    #pragma unroll
    for (int d = 32; d >= 1; d >>= 1)
        mk = max(mk, (unsigned)__shfl_xor((int)mk, d, 64));
    const float mrow = fival(mk);

    // ---- top-KK threshold: 16-iteration bisection on high 16 bits
    unsigned lo = 0, hi = mk >> 16;
    #pragma unroll 1
    while (lo < hi) {
        const unsigned mid = lo + ((hi - lo) >> 1);
        const unsigned tc = (mid + 1) << 16;      // key >= tc  <=>  hi16(key) > mid
        unsigned c = 0;
        #pragma unroll
        for (int e = 0; e < 32; ++e)
            c += (unsigned)__builtin_popcountll(__ballot(key[e] >= tc));
        if (c >= KK) lo = mid + 1; else hi = mid;
    }
    const unsigned t16 = lo;
    unsigned cnt_gt16 = 0, cnt_eq16 = 0, cm = 0;
    {
        const unsigned tc2 = (t16 + 1) << 16;
        #pragma unroll
        for (int e = 0; e < 32; ++e) {
            cnt_gt16 += (unsigned)__builtin_popcountll(__ballot(key[e] >= tc2));
            const bool eq = (key[e] >> 16) == t16;
            cnt_eq16 += (unsigned)__builtin_popcountll(__ballot(eq));
            if (eq) cm |= 1u << e;
        }
    }
    const unsigned rem = KK - cnt_gt16;           // in [1, cnt_eq16]

    // ---- exact (t_full, icut) among prefix-equal candidates
    unsigned tfull; int icut;
    if (cnt_eq16 == rem) {
        tfull = t16 << 16;                        // include ALL prefix-equal
        icut  = SEQ;
    } else {
        unsigned cmL = cm, wkk = 0; int wii = SEQ;
        #pragma unroll 1
        for (unsigned r2 = 0; r2 < rem; ++r2) {
            unsigned bk = 0; int bi = 0x7FFFFFFF; int be = -1;
            #pragma unroll
            for (int e = 0; e < 32; ++e) {
                if ((cmL >> e) & 1u) {
                    const unsigned kk2 = key[e];
                    const int ii = ((e >> 4) ? 1024 : 0)
                                 + 4 * ((rt + 64 * ((e >> 2) & 3)) ^ cx) + (e & 3);
                    if (kk2 > bk || (kk2 == bk && ii < bi)) { bk = kk2; bi = ii; be = e; }
                }
            }
            const unsigned mybk = bk; const int mybi = bi;
            #pragma unroll
            for (int d = 32; d >= 1; d >>= 1) {
                const unsigned ok = (unsigned)__shfl_xor((int)bk, d, 64);
                const int      oi = __shfl_xor(bi, d, 64);
                if (ok > bk || (ok == bk && oi < bi)) { bk = ok; bi = oi; }
            }
            wkk = bk; wii = bi;
            if (mybk == bk && mybi == bi && be >= 0) cmL &= ~(1u << be);
        }
        tfull = wkk; icut = wii;
    }

    // ---- P = exp(s - m) on selected, 0 elsewhere; single-bf16 overlay + denom
    unsigned short* PH = (unsigned short*)smem;   // [16][2048] bf16, row stride 2048
    unsigned* st = state + row * 8;
    {
        float psum = 0.f;
        #pragma unroll
        for (int j = 0; j < 8; ++j) {
            const int G = rt + 64 * (j & 3);
            const int gx = G ^ cx;
            const int gxg = (j >= 4 ? 256 : 0) + gx;
            const int kbase2 = (j >= 4 ? 1024 : 0) + 4 * gx;
            unsigned short ph[4];
            #pragma unroll
            for (int e = 0; e < 4; ++e) {
                const unsigned u = key[4*j+e];
                const int k = kbase2 + e;
                float pv = 0.f;
                if (u > tfull || (u == tfull && k <= icut)) pv = __expf(fival(u) - mrow);
                const unsigned short hh = bf16h(pv);
                ph[e] = hh;
                psum += bf16f(hh);
            }
            const int off = (row << 11) + ((((gxg >> 1) ^ cx)) << 3) + ((gxg & 1) << 2);
            uint2 wph; wph.x = (unsigned)ph[0] | ((unsigned)ph[1] << 16);
            wph.y = (unsigned)ph[2] | ((unsigned)ph[3] << 16);
            *(uint2*)&PH[off] = wph;
        }
        #pragma unroll
        for (int d = 32; d >= 1; d >>= 1) psum += __shfl_xor(psum, d, 64);
        if (rt == 0) st[5] = __float_as_uint(1.0f / psum);
    }
    __syncthreads();     // all P stripes + denominators ready

    // ---- PV via MFMA: wave = (kv-slice kq, dh-tile dt); bf16 P x (Vh+Vl)
    {
        const int dt = wv & 3, kq = wv >> 2;
        const int coll = lane & 15, kg = lane >> 4;
        const int c8 = coll & 7;
        f32x4 acc = {};
        for (int kc = 0; kc < 16; ++kc) {
            const int kv0 = kq * 512 + kc * 32 + kg * 8;
            const int aoff = (coll << 11) + (((kv0 >> 3) ^ c8) << 3);
            const short8 pa = *(const short8*)&PH[aoff];
            const size_t vidx = (((size_t)bh * 4 + dt) * 64 + kq * 16 + kc) * 512 + lane * 8;
            const short8 vh = *(const short8*)&Vfh[vidx];
            const short8 vl = *(const short8*)&Vfl[vidx];
            acc = __builtin_amdgcn_mfma_f32_16x16x32_bf16(pa, vh, acc, 0, 0, 0);
            acc = __builtin_amdgcn_mfma_f32_16x16x32_bf16(pa, vl, acc, 0, 0, 0);
        }
        if (kq > 0) *(f32x4*)&red[(((kq - 1) * 4 + dt) * 64 + lane) << 2] = acc;
        __syncthreads();     // PV partials
        if (kq == 0) {
            #pragma unroll
            for (int q2 = 0; q2 < 3; ++q2) {
                const f32x4 o = *(const f32x4*)&red[((q2 * 4 + dt) * 64 + lane) << 2];
                acc[0] += o[0]; acc[1] += o[1]; acc[2] += o[2]; acc[3] += o[3];
            }
            #pragma unroll
            for (int r = 0; r < 4; ++r) {
                const int rw = (lane >> 4) * 4 + r;
                const float inv = __uint_as_float(state[rw * 8 + 5]);
                const float v = acc[r] * inv;
                const int n = h * 64 + dt * 16 + coll;
                const int m = b * SEQ + q0 + rw;
                const int mblk = m >> 4, mrow2 = m & 15;
                const int ks = n >> 5, kg2 = (n >> 3) & 3, j2 = n & 7;
                const size_t a2 = (((size_t)mblk * 24 + ks) * 64 + kg2 * 16 + mrow2) * 8 + j2;
                const unsigned short vh2 = bf16h(v);
                AOh[a2] = vh2;
                AOl[a2] = bf16h(v - bf16f(vh2));
            }
        }
    }
}

// ---------------------------------------------------------------------------
extern "C" void kernel_launch(void* const* d_in, const int* in_sizes, int n_in,
                              void* d_out, int out_size, void* d_ws, size_t ws_size,
                              hipStream_t stream)
{
    const float* x  = (const float*)d_in[0];
    const float* Wq = (const float*)d_in[1];
    const float* bq = (const float*)d_in[2];
    const float* Wk = (const float*)d_in[3];
    const float* bk = (const float*)d_in[4];
    const float* Wv = (const float*)d_in[5];
    const float* bv = (const float*)d_in[6];
    const float* Wo = (const float*)d_in[7];
    const float* bo = (const float*)d_in[8];

    unsigned short* U = (unsigned short*)d_ws;
    const size_t SZ = (size_t)BATCH * SEQ * HIDDEN;   // 3,145,728
    const size_t WSZ = (size_t)HIDDEN * HIDDEN;       //   589,824
    unsigned short* xh  = U;                // later reused as AOh
    unsigned short* xl  = U + SZ;           // later reused as AOl
    unsigned short* Qh  = U + 2 * SZ;
    unsigned short* Ql  = U + 3 * SZ;
    unsigned short* Kh  = U + 4 * SZ;
    unsigned short* Kl  = U + 5 * SZ;
    unsigned short* Vth = U + 6 * SZ;
    unsigned short* Vtl = U + 7 * SZ;
    unsigned short* wqh = U + 8 * SZ;
    unsigned short* wql = wqh + WSZ;
    unsigned short* wkh = wqh + 2 * WSZ;
    unsigned short* wkl = wqh + 3 * WSZ;
    unsigned short* wvh = wqh + 4 * WSZ;
    unsigned short* wvl = wqh + 5 * WSZ;
    unsigned short* woh = wqh + 6 * WSZ;
    unsigned short* wol = wqh + 7 * WSZ;

    const dim3 gg(HIDDEN / 64, (BATCH * SEQ) / 64);

    cvt_frag<<<1536, 256, 0, stream>>>(x, xh, xl, BATCH * SEQ);
    cvt_frag_w<<<dim3(288, 4), 256, 0, stream>>>(Wq, Wk, Wv, Wo,
        wqh, wql, wkh, wkl, wvh, wvl, woh, wol);

    proj_fused<<<dim3(HIDDEN / 64, (BATCH * SEQ) / 64, 3), 256, 0, stream>>>(
        xh, xl, wqh, wql, wkh, wkl, wvh, wvl, bq, bk, bv, Qh, Ql, Kh, Kl, Vth, Vtl);

    const int shbytes = 16 * 1024 * 4 + 3072 * 4 + 16 * 8 * 4;   // 78,336 B
    hipFuncSetAttribute((const void*)sparse_attn,
                        hipFuncAttributeMaxDynamicSharedMemorySize, shbytes);
    sparse_attn<<<dim3(SEQ / QB, HEADS, BATCH), NTH, shbytes, stream>>>(
        Qh, Ql, Kh, Kl, Vth, Vtl, xh, xl);

    gemm_out<<<gg, 256, 0, stream>>>(xh, xl, woh, wol, bo, (float*)d_out);
}

// Round 10
// 463.360 us; speedup vs baseline: 1.2749x; 1.1562x over previous
//
#include <hip/hip_runtime.h>
#include <math.h>

#define HIDDEN 768
#define HEADS 12
#define HD 64
#define SEQ 2048
#define BATCH 2
#define KK 204
#define QB 16
#define NTH 1024

typedef __attribute__((ext_vector_type(8))) short short8;
typedef __attribute__((ext_vector_type(4))) float f32x4;

// monotonic float->uint key (larger float => larger key)
__device__ __forceinline__ unsigned fkey(float f) {
    unsigned u = __float_as_uint(f);
    return u ^ ((unsigned)((int)u >> 31) | 0x80000000u);
}
__device__ __forceinline__ float fival(unsigned k) {
    unsigned u = k ^ ((k & 0x80000000u) ? 0x80000000u : 0xFFFFFFFFu);
    return __uint_as_float(u);
}
__device__ __forceinline__ unsigned short bf16h(float f) {
    unsigned u = __float_as_uint(f);
    return (unsigned short)((u + 0x7FFFu + ((u >> 16) & 1u)) >> 16);
}
__device__ __forceinline__ float bf16f(unsigned short h) {
    return __uint_as_float(((unsigned)h) << 16);
}

// swizzled fp32 half-score LDS index (float4-group XOR row&7) — row stride 1024 f32
#define SIDXH(r,k) (((r)<<10) + (((((k)>>2) ^ ((r)&7))) << 2) + ((k)&3))

// ---------------------------------------------------------------------------
// Convert fp32 row-major [rows x 768] into MFMA fragment layout bf16 hi/lo.
// ---------------------------------------------------------------------------
__global__ __launch_bounds__(256)
void cvt_frag(const float* __restrict__ in, unsigned short* __restrict__ oh,
              unsigned short* __restrict__ ol, int rows)
{
    const int t = blockIdx.x * 256 + threadIdx.x;
    if (t >= rows * 96) return;
    const int lane = t & 63;
    const int kc   = (t >> 6) % 24;
    const int rblk = t / (24 * 64);
    const int r = rblk * 16 + (lane & 15);
    const int k = kc * 32 + (lane >> 4) * 8;
    const float4 a = *(const float4*)&in[(size_t)r * 768 + k];
    const float4 b = *(const float4*)&in[(size_t)r * 768 + k + 4];
    const float v[8] = {a.x, a.y, a.z, a.w, b.x, b.y, b.z, b.w};
    short8 sh, sl;
    #pragma unroll
    for (int j = 0; j < 8; ++j) {
        const unsigned short hh = bf16h(v[j]);
        sh[j] = (short)hh;
        sl[j] = (short)bf16h(v[j] - bf16f(hh));
    }
    *(short8*)&oh[(size_t)t * 8] = sh;
    *(short8*)&ol[(size_t)t * 8] = sl;
}

// Batched weight conversion: blockIdx.y selects which of the 4 weights.
__global__ __launch_bounds__(256)
void cvt_frag_w(const float* __restrict__ W0, const float* __restrict__ W1,
                const float* __restrict__ W2, const float* __restrict__ W3,
                unsigned short* __restrict__ o0h, unsigned short* __restrict__ o0l,
                unsigned short* __restrict__ o1h, unsigned short* __restrict__ o1l,
                unsigned short* __restrict__ o2h, unsigned short* __restrict__ o2l,
                unsigned short* __restrict__ o3h, unsigned short* __restrict__ o3l)
{
    const float* in; unsigned short *oh, *ol;
    switch (blockIdx.y) {
        case 0:  in = W0; oh = o0h; ol = o0l; break;
        case 1:  in = W1; oh = o1h; ol = o1l; break;
        case 2:  in = W2; oh = o2h; ol = o2l; break;
        default: in = W3; oh = o3h; ol = o3l; break;
    }
    const int t = blockIdx.x * 256 + threadIdx.x;
    if (t >= 768 * 96) return;
    const int lane = t & 63;
    const int kc   = (t >> 6) % 24;
    const int rblk = t / (24 * 64);
    const int r = rblk * 16 + (lane & 15);
    const int k = kc * 32 + (lane >> 4) * 8;
    const float4 a = *(const float4*)&in[(size_t)r * 768 + k];
    const float4 b = *(const float4*)&in[(size_t)r * 768 + k + 4];
    const float v[8] = {a.x, a.y, a.z, a.w, b.x, b.y, b.z, b.w};
    short8 sh, sl;
    #pragma unroll
    for (int j = 0; j < 8; ++j) {
        const unsigned short hh = bf16h(v[j]);
        sh[j] = (short)hh;
        sl[j] = (short)bf16h(v[j] - bf16f(hh));
    }
    *(short8*)&oh[(size_t)t * 8] = sh;
    *(short8*)&ol[(size_t)t * 8] = sl;
}

// ---------------------------------------------------------------------------
// Fused Q/K/V projection via split-bf16 MFMA: blockIdx.z selects weight set.
// ---------------------------------------------------------------------------
__global__ __launch_bounds__(256)
void proj_fused(const unsigned short* __restrict__ Ah, const unsigned short* __restrict__ Al,
                const unsigned short* __restrict__ Wqh, const unsigned short* __restrict__ Wql,
                const unsigned short* __restrict__ Wkh, const unsigned short* __restrict__ Wkl,
                const unsigned short* __restrict__ Wvh, const unsigned short* __restrict__ Wvl,
                const float* __restrict__ bq, const float* __restrict__ bk,
                const float* __restrict__ bv,
                unsigned short* __restrict__ Qh, unsigned short* __restrict__ Ql,
                unsigned short* __restrict__ Kh, unsigned short* __restrict__ Kl,
                unsigned short* __restrict__ Vth, unsigned short* __restrict__ Vtl)
{
    const unsigned short *Bh, *Bl; const float* bias;
    unsigned short *Oh, *Ol; int mode;
    if (blockIdx.z == 0)      { Bh = Wqh; Bl = Wql; bias = bq; Oh = Qh;  Ol = Ql;  mode = 0; }
    else if (blockIdx.z == 1) { Bh = Wkh; Bl = Wkl; bias = bk; Oh = Kh;  Ol = Kl;  mode = 0; }
    else                      { Bh = Wvh; Bl = Wvl; bias = bv; Oh = Vth; Ol = Vtl; mode = 1; }

    const int w = threadIdx.x >> 6, lane = threadIdx.x & 63;
    const int n0 = blockIdx.x * 64;
    const int m0 = blockIdx.y * 64 + w * 16;
    const int mblk = m0 >> 4;
    f32x4 acc[4] = {};
    for (int kc = 0; kc < 24; ++kc) {
        const short8 ah = *(const short8*)&Ah[((size_t)(mblk * 24 + kc) * 64 + lane) * 8];
        const short8 al = *(const short8*)&Al[((size_t)(mblk * 24 + kc) * 64 + lane) * 8];
        #pragma unroll
        for (int nt = 0; nt < 4; ++nt) {
            const int nblk = (n0 >> 4) + nt;
            const short8 bh8 = *(const short8*)&Bh[((size_t)(nblk * 24 + kc) * 64 + lane) * 8];
            const short8 bl8 = *(const short8*)&Bl[((size_t)(nblk * 24 + kc) * 64 + lane) * 8];
            acc[nt] = __builtin_amdgcn_mfma_f32_16x16x32_bf16(ah, bh8, acc[nt], 0, 0, 0);
            acc[nt] = __builtin_amdgcn_mfma_f32_16x16x32_bf16(ah, bl8, acc[nt], 0, 0, 0);
            acc[nt] = __builtin_amdgcn_mfma_f32_16x16x32_bf16(al, bh8, acc[nt], 0, 0, 0);
        }
    }
    const int col = lane & 15, rg = lane >> 4;
    #pragma unroll
    for (int nt = 0; nt < 4; ++nt) {
        const int n = n0 + nt * 16 + col;
        const int h = n >> 6, dh = n & 63;
        const float bb = bias[n];
        #pragma unroll
        for (int r = 0; r < 4; ++r) {
            const int m = m0 + rg * 4 + r;
            const int b = m >> 11, s = m & (SEQ - 1);
            const float v = acc[nt][r] + bb;
            const unsigned short vh = bf16h(v);
            if (mode == 0) {
                const int t = s >> 4, colq = s & 15;
                const int ks = dh >> 5, kg = (dh >> 3) & 3, j = dh & 7;
                const size_t addr = ((((size_t)(b * HEADS + h) * 128 + t) * 2 + ks) * 64 + kg * 16 + colq) * 8 + j;
                Oh[addr] = vh;
                Ol[addr] = bf16h(v - bf16f(vh));
            } else {
                const int dt = dh >> 4, colv = dh & 15;
                const int kc2 = s >> 5, kg = (s >> 3) & 3, j = s & 7;
                const size_t addr = ((((size_t)(b * HEADS + h) * 4 + dt) * 64 + kc2) * 64 + kg * 16 + colv) * 8 + j;
                Oh[addr] = vh;
                Ol[addr] = bf16h(v - bf16f(vh));
            }
        }
    }
}

// ---------------------------------------------------------------------------
// Output GEMM: out = AO @ Wo^T + bo (fp32 out), AO/Wo in fragment layout.
// ---------------------------------------------------------------------------
__global__ __launch_bounds__(256)
void gemm_out(const unsigned short* __restrict__ Ah, const unsigned short* __restrict__ Al,
              const unsigned short* __restrict__ Bh, const unsigned short* __restrict__ Bl,
              const float* __restrict__ bias, float* __restrict__ out)
{
    const int w = threadIdx.x >> 6, lane = threadIdx.x & 63;
    const int n0 = blockIdx.x * 64;
    const int m0 = blockIdx.y * 64 + w * 16;
    const int mblk = m0 >> 4;
    f32x4 acc[4] = {};
    for (int kc = 0; kc < 24; ++kc) {
        const short8 ah = *(const short8*)&Ah[((size_t)(mblk * 24 + kc) * 64 + lane) * 8];
        const short8 al = *(const short8*)&Al[((size_t)(mblk * 24 + kc) * 64 + lane) * 8];
        #pragma unroll
        for (int nt = 0; nt < 4; ++nt) {
            const int nblk = (n0 >> 4) + nt;
            const short8 bh8 = *(const short8*)&Bh[((size_t)(nblk * 24 + kc) * 64 + lane) * 8];
            const short8 bl8 = *(const short8*)&Bl[((size_t)(nblk * 24 + kc) * 64 + lane) * 8];
            acc[nt] = __builtin_amdgcn_mfma_f32_16x16x32_bf16(ah, bh8, acc[nt], 0, 0, 0);
            acc[nt] = __builtin_amdgcn_mfma_f32_16x16x32_bf16(ah, bl8, acc[nt], 0, 0, 0);
            acc[nt] = __builtin_amdgcn_mfma_f32_16x16x32_bf16(al, bh8, acc[nt], 0, 0, 0);
        }
    }
    const int col = lane & 15, rg = lane >> 4;
    #pragma unroll
    for (int nt = 0; nt < 4; ++nt) {
        const int n = n0 + nt * 16 + col;
        const float bb = bias[n];
        #pragma unroll
        for (int r = 0; r < 4; ++r) {
            const int m = m0 + rg * 4 + r;
            out[(size_t)m * HIDDEN + n] = acc[nt][r] + bb;
        }
    }
}

// ---------------------------------------------------------------------------
// Fused sparse attention, spill-free 2-blocks/CU edition.
// H=0 keys in regs (16); H=1 stays in LDS with hi16 packed in 8 regs.
// Select: 16-iter hi16 bisection; exact stage-2 + index bisection on demand.
// ---------------------------------------------------------------------------
__global__ __launch_bounds__(NTH, 8)
void sparse_attn(const unsigned short* __restrict__ Qfh, const unsigned short* __restrict__ Qfl,
                 const unsigned short* __restrict__ Kfh, const unsigned short* __restrict__ Kfl,
                 const unsigned short* __restrict__ Vfh, const unsigned short* __restrict__ Vfl,
                 unsigned short* __restrict__ AOh, unsigned short* __restrict__ AOl)
{
    extern __shared__ float smem[];
    float*    scores = smem;                       // [16][1024] f32; later PH [16][2048] bf16
    float*    red    = smem + 16 * 1024;           // PV partials (12KB)
    unsigned* state  = (unsigned*)(red + 3072);    // 16*8 (only [5]=inv cross-wave)

    // ---- XCD-aware work remap (3072 = 8 XCDs x 384 work items)
    const int f = blockIdx.x + 128 * (blockIdx.y + 12 * blockIdx.z);
    const int wk = (f & 7) * 384 + (f >> 3);
    const int qb = wk & 127;
    const int h  = (wk >> 7) % 12;
    const int b  = wk / 1536;
    const int q0 = qb * QB;
    const int bh = b * HEADS + h;

    const int tid = threadIdx.x;
    const int wv = tid >> 6, lane = tid & 63;
    const int row = wv, rt = lane;
    const int cx = row & 7;
    const int col = lane & 15, rg = lane >> 4;

    const size_t qoff = ((size_t)bh * 128 + qb) * 1024 + lane * 8;
    unsigned key[16];     // H=0 full keys
    unsigned khp[8];      // H=1 hi16, packed 2 per reg (elem 2j lo, 2j+1 hi)
    unsigned mk = 0;
    const float4* srow4 = (const float4*)(scores + (row << 10));

    // ---- Phase A, half 0 ----
    {
        const short8 qh0 = *(const short8*)&Qfh[qoff];
        const short8 qh1 = *(const short8*)&Qfh[qoff + 512];
        const short8 ql0 = *(const short8*)&Qfl[qoff];
        const short8 ql1 = *(const short8*)&Qfl[qoff + 512];
        for (int i = 0; i < 4; ++i) {
            const int t = wv * 4 + i;
            const size_t kb = ((size_t)bh * 128 + t) * 1024 + lane * 8;
            f32x4 c = {};
            {   // k-fragment half 0 (dh 0-31)
                const short8 kh0 = *(const short8*)&Kfh[kb];
                const short8 kl0 = *(const short8*)&Kfl[kb];
                c = __builtin_amdgcn_mfma_f32_16x16x32_bf16(qh0, kh0, c, 0, 0, 0);
                c = __builtin_amdgcn_mfma_f32_16x16x32_bf16(ql0, kh0, c, 0, 0, 0);
                c = __builtin_amdgcn_mfma_f32_16x16x32_bf16(qh0, kl0, c, 0, 0, 0);
            }
            {   // k-fragment half 1 (dh 32-63)
                const short8 kh1 = *(const short8*)&Kfh[kb + 512];
                const short8 kl1 = *(const short8*)&Kfl[kb + 512];
                c = __builtin_amdgcn_mfma_f32_16x16x32_bf16(qh1, kh1, c, 0, 0, 0);
                c = __builtin_amdgcn_mfma_f32_16x16x32_bf16(ql1, kh1, c, 0, 0, 0);
                c = __builtin_amdgcn_mfma_f32_16x16x32_bf16(qh1, kl1, c, 0, 0, 0);
            }
            const int kl2 = (wv * 4 + i) * 16 + col;
            #pragma unroll
            for (int r = 0; r < 4; ++r)
                scores[SIDXH(rg * 4 + r, kl2)] = c[r] * 0.125f;
        }
    }
    __syncthreads();                              // half-0 scores ready
    #pragma unroll
    for (int j = 0; j < 4; ++j) {                 // H=0 keys -> regs
        const float4 v = srow4[rt + 64 * j];
        key[4*j+0] = fkey(v.x); key[4*j+1] = fkey(v.y);
        key[4*j+2] = fkey(v.z); key[4*j+3] = fkey(v.w);
        mk = max(mk, max(max(key[4*j+0], key[4*j+1]), max(key[4*j+2], key[4*j+3])));
    }
    __syncthreads();                              // all key loads done before overwrite

    // ---- Phase A, half 1 ----
    {
        const short8 qh0 = *(const short8*)&Qfh[qoff];
        const short8 qh1 = *(const short8*)&Qfh[qoff + 512];
        const short8 ql0 = *(const short8*)&Qfl[qoff];
        const short8 ql1 = *(const short8*)&Qfl[qoff + 512];
        for (int i = 0; i < 4; ++i) {
            const int t = 64 + wv * 4 + i;
            const size_t kb = ((size_t)bh * 128 + t) * 1024 + lane * 8;
            f32x4 c = {};
            {
                const short8 kh0 = *(const short8*)&Kfh[kb];
                const short8 kl0 = *(const short8*)&Kfl[kb];
                c = __builtin_amdgcn_mfma_f32_16x16x32_bf16(qh0, kh0, c, 0, 0, 0);
                c = __builtin_amdgcn_mfma_f32_16x16x32_bf16(ql0, kh0, c, 0, 0, 0);
                c = __builtin_amdgcn_mfma_f32_16x16x32_bf16(qh0, kl0, c, 0, 0, 0);
            }
            {
                const short8 kh1 = *(const short8*)&Kfh[kb + 512];
                const short8 kl1 = *(const short8*)&Kfl[kb + 512];
                c = __builtin_amdgcn_mfma_f32_16x16x32_bf16(qh1, kh1, c, 0, 0, 0);
                c = __builtin_amdgcn_mfma_f32_16x16x32_bf16(ql1, kh1, c, 0, 0, 0);
                c = __builtin_amdgcn_mfma_f32_16x16x32_bf16(qh1, kl1, c, 0, 0, 0);
            }
            const int kl2 = (wv * 4 + i) * 16 + col;
            #pragma unroll
            for (int r = 0; r < 4; ++r)
                scores[SIDXH(rg * 4 + r, kl2)] = c[r] * 0.125f;
        }
    }
    __syncthreads();                              // half-1 scores ready (stay in LDS)
    #pragma unroll
    for (int j = 0; j < 4; ++j) {                 // H=1 hi16 -> packed regs
        const float4 v = srow4[rt + 64 * j];
        const unsigned u0 = fkey(v.x), u1 = fkey(v.y), u2 = fkey(v.z), u3 = fkey(v.w);
        mk = max(mk, max(max(u0, u1), max(u2, u3)));
        khp[2*j]   = (u0 >> 16) | (u1 & 0xFFFF0000u);
        khp[2*j+1] = (u2 >> 16) | (u3 & 0xFFFF0000u);
    }

    // ---- row max
    #pragma unroll
    for (int d = 32; d >= 1; d >>= 1)
        mk = max(mk, (unsigned)__shfl_xor((int)mk, d, 64));
    const float mrow = fival(mk);

    // ---- stage 1: bisect the hi16 of the KK-th largest key
    unsigned lo = 0, hi = mk >> 16;
    #pragma unroll 1
    while (lo < hi) {
        const unsigned mid = lo + ((hi - lo) >> 1);
        const unsigned m1 = mid + 1;
        unsigned c = 0;
        #pragma unroll
        for (int e = 0; e < 16; ++e)
            c += (unsigned)__builtin_popcountll(__ballot((key[e] >> 16) >= m1));
        #pragma unroll
        for (int p = 0; p < 8; ++p) {
            c += (unsigned)__builtin_popcountll(__ballot((khp[p] & 0xFFFFu) >= m1));
            c += (unsigned)__builtin_popcountll(__ballot((khp[p] >> 16) >= m1));
        }
        if (c >= KK) lo = m1; else hi = mid;
    }
    const unsigned t16 = lo;
    unsigned cnt_gt = 0, cnt_eq = 0;
    #pragma unroll
    for (int e = 0; e < 16; ++e) {
        const unsigned h16 = key[e] >> 16;
        cnt_gt += (unsigned)__builtin_popcountll(__ballot(h16 > t16));
        cnt_eq += (unsigned)__builtin_popcountll(__ballot(h16 == t16));
    }
    #pragma unroll
    for (int p = 0; p < 8; ++p) {
        const unsigned a0 = khp[p] & 0xFFFFu, a1 = khp[p] >> 16;
        cnt_gt += (unsigned)__builtin_popcountll(__ballot(a0 > t16));
        cnt_gt += (unsigned)__builtin_popcountll(__ballot(a1 > t16));
        cnt_eq += (unsigned)__builtin_popcountll(__ballot(a0 == t16));
        cnt_eq += (unsigned)__builtin_popcountll(__ballot(a1 == t16));
    }
    const unsigned rem = KK - cnt_gt;

    unsigned tfull = t16 << 16;
    int icut = SEQ;
    if (cnt_eq != rem) {
        // ---- stage 2: exact full-key bisection in [t16<<16, t16<<16|0xFFFF]
        unsigned lo2 = t16 << 16, hi2 = (t16 << 16) | 0xFFFFu;
        #pragma unroll 1
        while (lo2 < hi2) {
            const unsigned mid = lo2 + ((hi2 - lo2) >> 1);
            unsigned c = 0;
            #pragma unroll
            for (int e = 0; e < 16; ++e)
                c += (unsigned)__builtin_popcountll(__ballot(key[e] > mid));
            #pragma unroll
            for (int j = 0; j < 4; ++j) {
                const float4 v = srow4[rt + 64 * j];
                c += (unsigned)__builtin_popcountll(__ballot(fkey(v.x) > mid));
                c += (unsigned)__builtin_popcountll(__ballot(fkey(v.y) > mid));
                c += (unsigned)__builtin_popcountll(__ballot(fkey(v.z) > mid));
                c += (unsigned)__builtin_popcountll(__ballot(fkey(v.w) > mid));
            }
            if (c >= KK) lo2 = mid + 1; else hi2 = mid;
        }
        tfull = lo2;
        unsigned cgt = 0, ceq = 0;
        #pragma unroll
        for (int e = 0; e < 16; ++e) {
            cgt += (unsigned)__builtin_popcountll(__ballot(key[e] > tfull));
            ceq += (unsigned)__builtin_popcountll(__ballot(key[e] == tfull));
        }
        #pragma unroll
        for (int j = 0; j < 4; ++j) {
            const float4 v = srow4[rt + 64 * j];
            const unsigned u[4] = {fkey(v.x), fkey(v.y), fkey(v.z), fkey(v.w)};
            #pragma unroll
            for (int e = 0; e < 4; ++e) {
                cgt += (unsigned)__builtin_popcountll(__ballot(u[e] > tfull));
                ceq += (unsigned)__builtin_popcountll(__ballot(u[e] == tfull));
            }
        }
        const unsigned rem2 = KK - cgt;
        if (ceq > rem2) {
            // ---- index bisection for lowest-index-first tie cut
            unsigned lo3 = 0, hi3 = SEQ - 1;
            #pragma unroll 1
            while (lo3 < hi3) {
                const unsigned mid = (lo3 + hi3) >> 1;
                unsigned c = 0;
                #pragma unroll
                for (int e = 0; e < 16; ++e) {
                    const unsigned k = 4u * (unsigned)((rt + 64 * (e >> 2)) ^ cx) + (e & 3);
                    c += (unsigned)__builtin_popcountll(__ballot(key[e] == tfull && k <= mid));
                }
                #pragma unroll
                for (int j = 0; j < 4; ++j) {
                    const float4 v = srow4[rt + 64 * j];
                    const unsigned u[4] = {fkey(v.x), fkey(v.y), fkey(v.z), fkey(v.w)};
                    const unsigned gx = (unsigned)((rt + 64 * j) ^ cx);
                    #pragma unroll
                    for (int e = 0; e < 4; ++e) {
                        const unsigned k = 1024u + 4u * gx + e;
                        c += (unsigned)__builtin_popcountll(__ballot(u[e] == tfull && k <= mid));
                    }
                }
                if (c >= rem2) hi3 = mid; else lo3 = mid + 1;
            }
            icut = (int)lo3;
        }
    }

    // ---- P phase: read ALL H=1 scores first, then overlay-write P (bf16)
    unsigned short* PH = (unsigned short*)smem;   // [16][2048] bf16, row stride 2048
    unsigned* st = state + row * 8;
    {
        float psum = 0.f;
        uint2 w1[4];
        #pragma unroll
        for (int j = 0; j < 4; ++j) {             // H=1: read + compute (no writes yet)
            const float4 v = srow4[rt + 64 * j];
            const unsigned u[4] = {fkey(v.x), fkey(v.y), fkey(v.z), fkey(v.w)};
            const int gx = (rt + 64 * j) ^ cx;
            unsigned short ph[4];
            #pragma unroll
            for (int e = 0; e < 4; ++e) {
                const int k = 1024 + 4 * gx + e;
                float pv = 0.f;
                if (u[e] > tfull || (u[e] == tfull && k <= icut)) pv = __expf(fival(u[e]) - mrow);
                const unsigned short hh = bf16h(pv);
                ph[e] = hh;
                psum += bf16f(hh);
            }
            w1[j].x = (unsigned)ph[0] | ((unsigned)ph[1] << 16);
            w1[j].y = (unsigned)ph[2] | ((unsigned)ph[3] << 16);
        }
        #pragma unroll
        for (int j = 0; j < 4; ++j) {             // H=0: compute + write
            const int gx = (rt + 64 * j) ^ cx;
            unsigned short ph[4];
            #pragma unroll
            for (int e = 0; e < 4; ++e) {
                const unsigned u = key[4*j+e];
                const int k = 4 * gx + e;
                float pv = 0.f;
                if (u > tfull || (u == tfull && k <= icut)) pv = __expf(fival(u) - mrow);
                const unsigned short hh = bf16h(pv);
                ph[e] = hh;
                psum += bf16f(hh);
            }
            const int off = (row << 11) + ((((gx >> 1) ^ cx)) << 3) + ((gx & 1) << 2);
            uint2 wp; wp.x = (unsigned)ph[0] | ((unsigned)ph[1] << 16);
            wp.y = (unsigned)ph[2] | ((unsigned)ph[3] << 16);
            *(uint2*)&PH[off] = wp;
        }
        #pragma unroll
        for (int j = 0; j < 4; ++j) {             // H=1 writes
            const int gxg = 256 + ((rt + 64 * j) ^ cx);
            const int off = (row << 11) + ((((gxg >> 1) ^ cx)) << 3) + ((gxg & 1) << 2);
            *(uint2*)&PH[off] = w1[j];
        }
        #pragma unroll
        for (int d = 32; d >= 1; d >>= 1) psum += __shfl_xor(psum, d, 64);
        if (rt == 0) st[5] = __float_as_uint(1.0f / psum);
    }
    __syncthreads();     // all P stripes + denominators ready

    // ---- PV via MFMA: wave = (kv-slice kq, dh-tile dt); bf16 P x (Vh+Vl)
    {
        const int dt = wv & 3, kq = wv >> 2;
        const int coll = lane & 15, kg = lane >> 4;
        const int c8 = coll & 7;
        f32x4 acc = {};
        for (int kc = 0; kc < 16; ++kc) {
            const int kv0 = kq * 512 + kc * 32 + kg * 8;
            const int aoff = (coll << 11) + (((kv0 >> 3) ^ c8) << 3);
            const short8 pa = *(const short8*)&PH[aoff];
            const size_t vidx = (((size_t)bh * 4 + dt) * 64 + kq * 16 + kc) * 512 + lane * 8;
            const short8 vh = *(const short8*)&Vfh[vidx];
            const short8 vl = *(const short8*)&Vfl[vidx];
            acc = __builtin_amdgcn_mfma_f32_16x16x32_bf16(pa, vh, acc, 0, 0, 0);
            acc = __builtin_amdgcn_mfma_f32_16x16x32_bf16(pa, vl, acc, 0, 0, 0);
        }
        if (kq > 0) *(f32x4*)&red[(((kq - 1) * 4 + dt) * 64 + lane) << 2] = acc;
        __syncthreads();     // PV partials
        if (kq == 0) {
            #pragma unroll
            for (int q2 = 0; q2 < 3; ++q2) {
                const f32x4 o = *(const f32x4*)&red[((q2 * 4 + dt) * 64 + lane) << 2];
                acc[0] += o[0]; acc[1] += o[1]; acc[2] += o[2]; acc[3] += o[3];
            }
            #pragma unroll
            for (int r = 0; r < 4; ++r) {
                const int rw = (lane >> 4) * 4 + r;
                const float inv = __uint_as_float(state[rw * 8 + 5]);
                const float v = acc[r] * inv;
                const int n = h * 64 + dt * 16 + coll;
                const int m = b * SEQ + q0 + rw;
                const int mblk = m >> 4, mrow2 = m & 15;
                const int ks = n >> 5, kg2 = (n >> 3) & 3, j2 = n & 7;
                const size_t a2 = (((size_t)mblk * 24 + ks) * 64 + kg2 * 16 + mrow2) * 8 + j2;
                const unsigned short vh2 = bf16h(v);
                AOh[a2] = vh2;
                AOl[a2] = bf16h(v - bf16f(vh2));
            }
        }
    }
}

// ---------------------------------------------------------------------------
extern "C" void kernel_launch(void* const* d_in, const int* in_sizes, int n_in,
                              void* d_out, int out_size, void* d_ws, size_t ws_size,
                              hipStream_t stream)
{
    const float* x  = (const float*)d_in[0];
    const float* Wq = (const float*)d_in[1];
    const float* bq = (const float*)d_in[2];
    const float* Wk = (const float*)d_in[3];
    const float* bk = (const float*)d_in[4];
    const float* Wv = (const float*)d_in[5];
    const float* bv = (const float*)d_in[6];
    const float* Wo = (const float*)d_in[7];
    const float* bo = (const float*)d_in[8];

    unsigned short* U = (unsigned short*)d_ws;
    const size_t SZ = (size_t)BATCH * SEQ * HIDDEN;   // 3,145,728
    const size_t WSZ = (size_t)HIDDEN * HIDDEN;       //   589,824
    unsigned short* xh  = U;                // later reused as AOh
    unsigned short* xl  = U + SZ;           // later reused as AOl
    unsigned short* Qh  = U + 2 * SZ;
    unsigned short* Ql  = U + 3 * SZ;
    unsigned short* Kh  = U + 4 * SZ;
    unsigned short* Kl  = U + 5 * SZ;
    unsigned short* Vth = U + 6 * SZ;
    unsigned short* Vtl = U + 7 * SZ;
    unsigned short* wqh = U + 8 * SZ;
    unsigned short* wql = wqh + WSZ;
    unsigned short* wkh = wqh + 2 * WSZ;
    unsigned short* wkl = wqh + 3 * WSZ;
    unsigned short* wvh = wqh + 4 * WSZ;
    unsigned short* wvl = wqh + 5 * WSZ;
    unsigned short* woh = wqh + 6 * WSZ;
    unsigned short* wol = wqh + 7 * WSZ;

    const dim3 gg(HIDDEN / 64, (BATCH * SEQ) / 64);

    cvt_frag<<<1536, 256, 0, stream>>>(x, xh, xl, BATCH * SEQ);
    cvt_frag_w<<<dim3(288, 4), 256, 0, stream>>>(Wq, Wk, Wv, Wo,
        wqh, wql, wkh, wkl, wvh, wvl, woh, wol);

    proj_fused<<<dim3(HIDDEN / 64, (BATCH * SEQ) / 64, 3), 256, 0, stream>>>(
        xh, xl, wqh, wql, wkh, wkl, wvh, wvl, bq, bk, bv, Qh, Ql, Kh, Kl, Vth, Vtl);

    const int shbytes = 16 * 1024 * 4 + 3072 * 4 + 16 * 8 * 4;   // 78,336 B
    hipFuncSetAttribute((const void*)sparse_attn,
                        hipFuncAttributeMaxDynamicSharedMemorySize, shbytes);
    sparse_attn<<<dim3(SEQ / QB, HEADS, BATCH), NTH, shbytes, stream>>>(
        Qh, Ql, Kh, Kl, Vth, Vtl, xh, xl);

    gemm_out<<<gg, 256, 0, stream>>>(xh, xl, woh, wol, bo, (float*)d_out);
}